// Round 4
// baseline (141.326 us; speedup 1.0000x reference)
//
#include <hip/hip_runtime.h>
#include <math.h>

typedef float v2f __attribute__((ext_vector_type(2)));
typedef float v4f __attribute__((ext_vector_type(4)));

#define LT(i,j) ((i)*((i)+1)/2 + (j))

// reflect index into [0,512)
__device__ __forceinline__ int reflect512(int i) {
  int a = (i < 0) ? -i : i;
  int b = 1022 - a;
  return (a < b) ? a : b;
}

// ---- halo'd interleaved buffer: zb[b][520][520][12] f32, halo=4, reflected.
// pixel layout: [x0x1][x2x3][x4x5][y0y1][y2y3][y4y5] (3 x 16B)
constexpr int HB  = 520;          // 512 + 2*4 halo
constexpr int PS  = 12;           // words per pixel
constexpr int RS  = HB * PS;      // words per halo row (6240)

// 4 pixels per thread. Interior column-groups use dwordx4 loads from the
// planar inputs; only the edge groups take the reflect path.
__global__ __launch_bounds__(256)
void prep_interleave4(const float* __restrict__ xg, const float* __restrict__ yg,
                      float* __restrict__ zb) {
  constexpr int H = 512, W = 512, HW = H * W;
  constexpr int WQ = HB / 4;                  // 130 groups of 4 columns
  const int idx = blockIdx.x * 256 + threadIdx.x;
  if (idx >= 2 * HB * WQ) return;
  const int b  = idx / (HB * WQ);
  const int r2 = idx - b * (HB * WQ);
  const int hr = r2 / WQ;
  const int q  = r2 - hr * WQ;
  const int h  = reflect512(hr - 4);
  const int w0 = q * 4 - 4;                   // first source col (halo - 4)
  const size_t rowbase = (size_t)b * 6 * HW + (size_t)h * W;

  float xv[6][4], yv[6][4];
  if (w0 >= 0 && w0 + 3 < W) {
    #pragma unroll
    for (int c = 0; c < 6; ++c) {
      const v4f vx = *(const v4f*)(xg + rowbase + (size_t)c * HW + w0);
      const v4f vy = *(const v4f*)(yg + rowbase + (size_t)c * HW + w0);
      #pragma unroll
      for (int j = 0; j < 4; ++j) { xv[c][j] = vx[j]; yv[c][j] = vy[j]; }
    }
  } else {
    #pragma unroll
    for (int j = 0; j < 4; ++j) {
      const int w = reflect512(w0 + j);
      #pragma unroll
      for (int c = 0; c < 6; ++c) {
        xv[c][j] = xg[rowbase + (size_t)c * HW + w];
        yv[c][j] = yg[rowbase + (size_t)c * HW + w];
      }
    }
  }

  float* o = zb + ((size_t)(b * HB + hr) * HB + q * 4) * PS;
  #pragma unroll
  for (int j = 0; j < 4; ++j) {
    v4f p0 = {xv[0][j], xv[1][j], xv[2][j], xv[3][j]};
    v4f p1 = {xv[4][j], xv[5][j], yv[0][j], yv[1][j]};
    v4f p2 = {yv[2][j], yv[3][j], yv[4][j], yv[5][j]};
    *(v4f*)(o + j * PS + 0) = p0;
    *(v4f*)(o + j * PS + 4) = p1;
    *(v4f*)(o + j * PS + 8) = p2;
  }
}

// Gram entry g[a][b] (a>=b) from the 2x2-block pk accumulators.
__device__ __forceinline__ float gget(const v2f* accd, const v2f* accs,
                                      int a, int b) {
  const int t = LT(a >> 1, b >> 1);
  if (((a & 1) == 0) && ((b & 1) == 0)) return accd[t].x;
  if (((a & 1) == 1) && ((b & 1) == 1)) return accd[t].y;
  if ((a & 1) == 0) return accs[t].x;
  return accs[t].y;
}

// Packed-lower SPD 6x6 -> packed-lower L^{-1} in place. Divide/sqrt-free.
__device__ __forceinline__ void cholinv6(float* a) {
  #pragma unroll
  for (int j = 0; j < 6; ++j) {
    float d = a[LT(j,j)];
    #pragma unroll
    for (int p = 0; p < j; ++p) d -= a[LT(j,p)] * a[LT(j,p)];
    const float rd = __builtin_amdgcn_rsqf(d);
    a[LT(j,j)] = rd;
    #pragma unroll
    for (int i = j + 1; i < 6; ++i) {
      float s = a[LT(i,j)];
      #pragma unroll
      for (int p = 0; p < j; ++p) s -= a[LT(i,p)] * a[LT(j,p)];
      a[LT(i,j)] = s * rd;
    }
  }
  #pragma unroll
  for (int j = 0; j < 6; ++j) {
    #pragma unroll
    for (int i = j + 1; i < 6; ++i) {
      float s = 0.0f;
      #pragma unroll
      for (int p = j; p < i; ++p) s += a[LT(i,p)] * a[LT(p,j)];
      a[LT(i,j)] = -s * a[LT(i,i)];
    }
  }
}

// +/- one pixel's products into the Gram accumulators (p -> 12 floats).
template <bool ADD>
__device__ __forceinline__ void px_acc(const float* __restrict__ p,
                                       v2f* zs, v2f* accd, v2f* accs) {
  const v4f l0 = *(const v4f*)(p + 0);
  const v4f l1 = *(const v4f*)(p + 4);
  const v4f l2 = *(const v4f*)(p + 8);
  v2f z[6];
  z[0] = l0.lo; z[1] = l0.hi;
  z[2] = l1.lo; z[3] = l1.hi;
  z[4] = l2.lo; z[5] = l2.hi;
  #pragma unroll
  for (int q = 0; q < 6; ++q) zs[q] = ADD ? (zs[q] + z[q]) : (zs[q] - z[q]);
  int t = 0;
  #pragma unroll
  for (int Kp = 0; Kp < 6; ++Kp) {
    #pragma unroll
    for (int Pp = 0; Pp <= Kp; ++Pp) {
      const v2f c  = z[Pp];
      const v2f cs = __builtin_shufflevector(c, c, 1, 0);
      const v2f a  = ADD ? z[Kp] : -z[Kp];
      accd[t] = __builtin_elementwise_fma(a, c,  accd[t]);
      accs[t] = __builtin_elementwise_fma(a, cs, accs[t]);
      ++t;
    }
  }
}

// +/- one window row's K pixels (global path, used for LEAVE rows).
template <int K, bool ADD>
__device__ __forceinline__ void row_acc_g(const float* __restrict__ p,
                                          v2f* zs, v2f* accd, v2f* accs) {
  #pragma unroll
  for (int dx = 0; dx < K; ++dx) px_acc<ADD>(p + dx * PS, zs, accd, accs);
}

template <int K>
__device__ __forceinline__ float emit_sim(const v2f* zs, const v2f* accd,
                                          const v2f* accs) {
  constexpr float inv_n = 1.0f / (K * K);
  float mx[6], my[6];
  #pragma unroll
  for (int i = 0; i < 6; ++i) {
    mx[i] = ((i & 1) ? zs[i >> 1].y : zs[i >> 1].x) * inv_n;
    my[i] = ((i & 1) ? zs[3 + (i >> 1)].y : zs[3 + (i >> 1)].x) * inv_n;
  }
  float ax[21];
  {
    int t = 0;
    #pragma unroll
    for (int i = 0; i < 6; ++i)
      #pragma unroll
      for (int j = 0; j <= i; ++j) {
        const float e = (i == j) ? 1e-6f : 0.0f;
        ax[t] = gget(accd, accs, i, j) * inv_n - mx[i] * mx[j] + e;
        ++t;
      }
  }
  cholinv6(ax);
  float ay[21];
  {
    int t = 0;
    #pragma unroll
    for (int i = 0; i < 6; ++i)
      #pragma unroll
      for (int j = 0; j <= i; ++j) {
        const float e = (i == j) ? 1e-6f : 0.0f;
        ay[t] = gget(accd, accs, 6 + i, 6 + j) * inv_n - my[i] * my[j] + e;
        ++t;
      }
  }
  cholinv6(ay);
  float cxy[36];
  #pragma unroll
  for (int i = 0; i < 6; ++i)
    #pragma unroll
    for (int j = 0; j < 6; ++j)
      cxy[i * 6 + j] = fmaf(-mx[i], my[j], gget(accd, accs, 6 + j, i) * inv_n);
  float sim = 0.0f;
  #pragma unroll
  for (int i = 0; i < 6; ++i) {
    float di = 0.0f;
    #pragma unroll
    for (int j = 0; j <= i; ++j) {
      float inner = 0.0f;
      #pragma unroll
      for (int k = i; k < 6; ++k) inner += cxy[j * 6 + k] * ay[LT(k, i)];
      di += ax[LT(i, j)] * inner;
    }
    sim += fabsf(di);
  }
  return sim * (1.0f / 6.0f);
}

// LDS-staged sliding window. 16 strips (g) x 16 cols (tx) per block, V=8
// outputs per strip. Per phase t: the strip's ENTER row comes from LDS
// (staged coalesced, double-buffered); the LEAVE row re-reads global (L1/L2
// warm). Enter row t = halo row hbase+4-R+t; leave (t>=K) = enter row t-K.
template <int R, int V>
__device__ __forceinline__ void run_lds(const float* __restrict__ zb,
                                        float* __restrict__ out, int b, int ri,
                                        float* __restrict__ lds) {
  constexpr int K    = 2 * R + 1;
  constexpr int H = 512, W = 512;
  constexpr int SEGW = 16 + 2 * R;       // pixels per staged row segment
  constexpr int CH   = SEGW * 3;         // 16B chunks per segment
  constexpr int NCH  = 16 * CH;          // chunks per buffer fill
  constexpr int NI   = (NCH + 255) / 256;
  constexpr int SEGS = 288;              // words per segment slot (max 24*12)
  constexpr int BUFW = 16 * SEGS;        // words per buffer
  constexpr int PH   = K + V - 1;        // phases (t = 0..PH-1)
  constexpr int RSB  = RS * 4;           // bytes per halo row

  const int tid = threadIdx.x;
  const int tx = tid & 15;
  const int g  = tid >> 4;
  const int h0 = blockIdx.y * (16 * V);
  const int w0 = blockIdx.x * 16;
  const int hbase = h0 + g * V;
  const int wc = w0 + tx;

  // ---- staging map: chunk q -> (strip sg, chunk off) ----
  int  goff[NI];   // byte offset (within b-plane) of phase-0 enter chunk
  int  loff[NI];   // word offset within an LDS buffer
  bool act[NI];
  #pragma unroll
  for (int i = 0; i < NI; ++i) {
    int q = tid + 256 * i;
    act[i] = (q < NCH);
    if (!act[i]) q = 0;
    const int sg = q / CH;
    const int of = q - sg * CH;
    goff[i] = ((h0 + V * sg + 4 - R) * RS + (w0 + 4 - R) * PS + of * 4) * 4;
    loff[i] = sg * SEGS + of * 4;
  }
  const char* zbB = (const char*)(zb + (size_t)b * HB * RS);
  // leave-row global base (lane's leftmost window pixel of output row hbase)
  const float* lbase = zb + (size_t)b * HB * RS
                     + (size_t)(hbase + 4 - R) * RS + (size_t)(wc + 4 - R) * PS;

  // ---- prologue: stage phase 0 into buffer 0 ----
  #pragma unroll
  for (int i = 0; i < NI; ++i) {
    if (act[i]) {
      const v4f v = *(const v4f*)(zbB + goff[i]);
      *(v4f*)(lds + loff[i]) = v;
    }
  }
  __syncthreads();

  v2f zs[6]    = {};
  v2f accd[21] = {};
  v2f accs[21] = {};

  #pragma unroll 1
  for (int t = 0; t < PH; ++t) {
    // 1. issue next phase's stage loads (latency hides under consume+emit)
    v4f st[NI];
    const bool more = (t + 1 < PH);
    if (more) {
      #pragma unroll
      for (int i = 0; i < NI; ++i)
        if (act[i]) st[i] = *(const v4f*)(zbB + goff[i] + (t + 1) * RSB);
    }
    // 2. consume enter row from LDS buf[t&1]
    {
      const float* ep = lds + (t & 1) * BUFW + g * SEGS + tx * 12;
      #pragma unroll
      for (int dx = 0; dx < K; ++dx)
        px_acc<true>(ep + dx * 12, zs, accd, accs);
    }
    // 3. leave row via global (L1/L2-warm; staged as enter K phases ago)
    if (t >= K)
      row_acc_g<K, false>(lbase + (size_t)(t - K) * RS, zs, accd, accs);
    // 4. emit
    if (t >= K - 1) {
      const float sim = emit_sim<K>(zs, accd, accs);
      out[((size_t)((b * H + hbase + (t - K + 1)) * W + wc)) * 2 + ri] = sim;
    }
    // 5. write staged regs into buf[(t+1)&1]
    if (more) {
      float* wp = lds + ((t + 1) & 1) * BUFW;
      #pragma unroll
      for (int i = 0; i < NI; ++i)
        if (act[i]) *(v4f*)(wp + loff[i]) = st[i];
    }
    __syncthreads();
  }
}

// z in {0,1}: r=2 batch z; z in {2,3}: r=4 batch z-2.
__global__ __launch_bounds__(256, 2)
void cca_stage(const float* __restrict__ zb, float* __restrict__ out) {
  __shared__ float lds[2][16][288];   // 36,864 B (double-buffered enter rows)
  const int z = blockIdx.z;
  if (z < 2) run_lds<2, 8>(zb, out, z, 0, &lds[0][0][0]);
  else       run_lds<4, 8>(zb, out, z - 2, 1, &lds[0][0][0]);
}

extern "C" void kernel_launch(void* const* d_in, const int* in_sizes, int n_in,
                              void* d_out, int out_size, void* d_ws, size_t ws_size,
                              hipStream_t stream) {
  const float* x = (const float*)d_in[0];
  const float* y = (const float*)d_in[1];
  float* out = (float*)d_out;
  float* zb  = (float*)d_ws;   // needs 2*520*520*12*4 B = 25.96 MB

  {
    const int n = 2 * HB * (HB / 4);   // 4 px per thread
    prep_interleave4<<<dim3((n + 255) / 256), dim3(256), 0, stream>>>(x, y, zb);
  }
  dim3 grid(512 / 16, 512 / (16 * 8), 4);   // 32 x 4 x 4 = 512 blocks
  cca_stage<<<grid, dim3(256), 0, stream>>>(zb, out);
}